// Round 1
// baseline (540.682 us; speedup 1.0000x reference)
//
#include <hip/hip_runtime.h>
#include <hip/hip_bf16.h>

// GaussSpatialConv: out[i,:] = softmax_j(-||x_i-y_j||^2 * 50) @ y_fea
// B=1, N=M=12288, D=16, fp32.
//
// Structure: 3 kernels.
//  1) kmin: per-row min squared distance (softmax max-shift), atomicMin on uint bits.
//  2) kacc: weighted accumulation, lanes=rows / j wave-uniform (scalar y/fea loads),
//     j split into CHUNKS for parallelism, atomicAdd partial (s, acc) per row.
//  3) kdiv: out /= s.

#define NROWS 12288
#define MCOLS 12288
#define DFEA  16
#define CHUNKS 32
#define JCHUNK (MCOLS / CHUNKS)   // 384
#define ROWG  (NROWS / 64)        // 192 row-groups of 64 rows (one per lane)

// inv(2*sigma^2) = 50; fold log2(e) so we can use hardware exp2 (v_exp_f32).
#define CC   72.13475204444817f   // 50 * log2(e)

__global__ __launch_bounds__(256) void kmin_kernel(const float* __restrict__ x,
                                                   const float* __restrict__ y,
                                                   unsigned int* __restrict__ rowmin) {
    int tid  = blockIdx.x * 256 + threadIdx.x;
    int wave = __builtin_amdgcn_readfirstlane(tid >> 6);   // force wave-uniform
    int lane = threadIdx.x & 63;
    int rg   = wave / CHUNKS;
    int ch   = wave - rg * CHUNKS;
    int row  = rg * 64 + lane;

    float x0 = x[row * 3 + 0];
    float x1 = x[row * 3 + 1];
    float x2 = x[row * 3 + 2];

    int j0 = ch * JCHUNK;
    float mn = 3.4e38f;
    #pragma unroll 4
    for (int j = j0; j < j0 + JCHUNK; ++j) {
        // j is wave-uniform -> these should scalarize to s_load
        float dx = x0 - y[3 * j + 0];
        float dy = x1 - y[3 * j + 1];
        float dz = x2 - y[3 * j + 2];
        float d2 = fmaf(dx, dx, fmaf(dy, dy, dz * dz));
        mn = fminf(mn, d2);
    }
    // d2 >= 0 always, so uint bit-compare == float compare.
    atomicMin(rowmin + row, __float_as_uint(mn));
}

__global__ __launch_bounds__(256) void kacc_kernel(const float* __restrict__ x,
                                                   const float* __restrict__ y,
                                                   const float* __restrict__ fea,
                                                   const float* __restrict__ rowmin,
                                                   float* __restrict__ ssum,
                                                   float* __restrict__ out) {
    int tid  = blockIdx.x * 256 + threadIdx.x;
    int wave = __builtin_amdgcn_readfirstlane(tid >> 6);
    int lane = threadIdx.x & 63;
    int rg   = wave / CHUNKS;
    int ch   = wave - rg * CHUNKS;
    int row  = rg * 64 + lane;

    float x0 = x[row * 3 + 0];
    float x1 = x[row * 3 + 1];
    float x2 = x[row * 3 + 2];
    float rm = rowmin[row];          // coalesced per-lane load
    float rmc = rm * CC;             // fold shift: t = rmc - d2*CC

    float acc[DFEA];
    #pragma unroll
    for (int k = 0; k < DFEA; ++k) acc[k] = 0.0f;
    float s = 0.0f;

    int j0 = ch * JCHUNK;
    #pragma unroll 2
    for (int j = j0; j < j0 + JCHUNK; ++j) {
        float dx = x0 - y[3 * j + 0];
        float dy = x1 - y[3 * j + 1];
        float dz = x2 - y[3 * j + 2];
        float d2 = fmaf(dx, dx, fmaf(dy, dy, dz * dz));
        float w  = exp2f(fmaf(d2, -CC, rmc));   // exp((rowmin-d2)*inv2s2), exact shift
        s += w;
        #pragma unroll
        for (int k = 0; k < DFEA; ++k) {
            acc[k] = fmaf(w, fea[j * DFEA + k], acc[k]);  // fea_j uniform -> SGPR operand
        }
    }

    atomicAdd(ssum + row, s);
    #pragma unroll
    for (int k = 0; k < DFEA; ++k) {
        atomicAdd(out + row * DFEA + k, acc[k]);
    }
}

__global__ __launch_bounds__(256) void kdiv_kernel(float* __restrict__ out,
                                                   const float* __restrict__ ssum) {
    int t = blockIdx.x * 256 + threadIdx.x;
    out[t] = out[t] / ssum[t >> 4];   // s >= 1 guaranteed (w=1 at the rowmin j)
}

extern "C" void kernel_launch(void* const* d_in, const int* in_sizes, int n_in,
                              void* d_out, int out_size, void* d_ws, size_t ws_size,
                              hipStream_t stream) {
    const float* x   = (const float*)d_in[0];   // [N,3]
    const float* y   = (const float*)d_in[1];   // [M,3]
    const float* fea = (const float*)d_in[2];   // [M,16]
    float* out = (float*)d_out;                 // [N,16]

    unsigned int* rowmin = (unsigned int*)d_ws;            // N uints
    float*        ssum   = (float*)d_ws + NROWS;           // N floats

    // rowmin sentinel: 0xFFFFFFFF is > any non-negative float's bits.
    hipMemsetAsync(d_ws, 0xFF, (size_t)NROWS * 4, stream);
    hipMemsetAsync((void*)ssum, 0, (size_t)NROWS * 4, stream);
    hipMemsetAsync(d_out, 0, (size_t)NROWS * DFEA * 4, stream);

    dim3 grid(ROWG * CHUNKS / 4);   // 4 waves per 256-thread block
    kmin_kernel<<<grid, 256, 0, stream>>>(x, y, rowmin);
    kacc_kernel<<<grid, 256, 0, stream>>>(x, y, fea, (const float*)rowmin, ssum, out);
    kdiv_kernel<<<(NROWS * DFEA) / 256, 256, 0, stream>>>(out, ssum);
}

// Round 2
// 385.623 us; speedup vs baseline: 1.4021x; 1.4021x over previous
//
#include <hip/hip_runtime.h>
#include <hip/hip_bf16.h>

// GaussSpatialConv: out[i,:] = softmax_j(-||x_i-y_j||^2 * 50) @ y_fea
// B=1, N=M=12288, D=16, fp32.
//
// R2: latency fix. Block = 256 rows (lane->row), j-stream staged through
// double-buffered LDS tiles (cooperative coalesced global loads), inner loop
// reads wave-uniform (broadcast) ds_read_b128. float2 accumulators to get
// v_pk_fma_f32. j split into CH chunks for grid parallelism, combined via
// atomicAdd partials.

#define NROWS 12288
#define MCOLS 12288
#define DFEA  16

#define CH    16                    // j-chunks for kacc
#define JCH   (MCOLS / CH)          // 768 js per block
#define TJ    128                   // js per LDS tile (kacc)
#define NT    (JCH / TJ)            // 6 tiles
#define REC   20                    // floats per record: y4 + fea16 (80 B)

#define CHM   16                    // j-chunks for kmin
#define JCHM  (MCOLS / CHM)         // 768
#define TJM   256                   // js per tile (kmin), 4-float records
#define NTM   (JCHM / TJM)          // 3

// inv(2*sigma^2) = 50; fold log2(e) for hardware v_exp_f32.
#define CC   72.13475204444817f

// ---------------------------------------------------------------- kmin ----
__global__ __launch_bounds__(256, 4) void kmin_kernel(const float* __restrict__ x,
                                                      const float* __restrict__ y,
                                                      unsigned int* __restrict__ rowmin) {
    __shared__ float sm[2][TJM * 4];
    int t   = threadIdx.x;
    int rb  = blockIdx.x / CHM;       // 48 row-blocks
    int ch  = blockIdx.x - rb * CHM;
    int row = rb * 256 + t;
    int j0  = ch * JCHM;

    float x0 = x[row * 3 + 0];
    float x1 = x[row * 3 + 1];
    float x2 = x[row * 3 + 2];

    // prefetch tile 0 into regs (thread t stages y row j0+t)
    const float* yp = y + (size_t)(j0 + t) * 3;
    float a0 = yp[0], a1 = yp[1], a2 = yp[2];

    float mn = 3.4e38f;
    int p = 0;
    for (int tt = 0; tt < NTM; ++tt) {
        // store staged regs -> LDS
        *(float4*)(&sm[p][t * 4]) = make_float4(a0, a1, a2, 0.0f);
        __syncthreads();
        // prefetch next tile while computing
        if (tt + 1 < NTM) {
            const float* yn = y + (size_t)(j0 + (tt + 1) * TJM + t) * 3;
            a0 = yn[0]; a1 = yn[1]; a2 = yn[2];
        }
        const float* bp = sm[p];
        #pragma unroll 8
        for (int jj = 0; jj < TJM; ++jj) {
            float4 yv = *(const float4*)(bp + jj * 4);   // broadcast read
            float dx = x0 - yv.x;
            float dy = x1 - yv.y;
            float dz = x2 - yv.z;
            float d2 = fmaf(dx, dx, fmaf(dy, dy, dz * dz));
            mn = fminf(mn, d2);
        }
        __syncthreads();   // note: single-sync would suffice w/ 2 buffers; keep simple
        p ^= 1;
    }
    atomicMin(rowmin + row, __float_as_uint(mn));
}

// ---------------------------------------------------------------- kacc ----
__global__ __launch_bounds__(256, 4) void kacc_kernel(const float* __restrict__ x,
                                                      const float* __restrict__ y,
                                                      const float* __restrict__ fea,
                                                      const float* __restrict__ rowmin,
                                                      float* __restrict__ ssum,
                                                      float* __restrict__ out) {
    __shared__ float smem[2][TJ * REC];   // 2 x 10 KB
    int t   = threadIdx.x;
    int rb  = blockIdx.x / CH;            // 48 row-blocks
    int ch  = blockIdx.x - rb * CH;
    int row = rb * 256 + t;
    int j0  = ch * JCH;

    float x0 = x[row * 3 + 0];
    float x1 = x[row * 3 + 1];
    float x2 = x[row * 3 + 2];
    float rmc = rowmin[row] * CC;         // shift: w = exp2(rmc - d2*CC)

    float2 acc[8];
    #pragma unroll
    for (int k = 0; k < 8; ++k) acc[k] = make_float2(0.0f, 0.0f);
    float s = 0.0f;

    // ---- staging registers for tile prefetch ----
    // y: threads 0..127 stage y row (j0+t): 3 floats
    // fea: every thread stages 2 float4: idx = t and t+256; j = idx>>2, quad = idx&3
    float a0 = 0, a1 = 0, a2 = 0;
    float4 f0, f1;
    {
        if (t < TJ) {
            const float* yp = y + (size_t)(j0 + t) * 3;
            a0 = yp[0]; a1 = yp[1]; a2 = yp[2];
        }
        const float* fp0 = fea + (size_t)(j0 + (t >> 2)) * DFEA + (t & 3) * 4;
        f0 = *(const float4*)fp0;
        f1 = *(const float4*)(fp0 + 64 * DFEA);   // idx + 256 -> j + 64
    }

    int p = 0;
    for (int tt = 0; tt < NT; ++tt) {
        float* buf = smem[p];
        if (t < TJ) *(float4*)(buf + t * REC) = make_float4(a0, a1, a2, 0.0f);
        {
            int j = t >> 2, q = t & 3;
            *(float4*)(buf + j * REC + 4 + q * 4) = f0;
            *(float4*)(buf + (j + 64) * REC + 4 + q * 4) = f1;
        }
        __syncthreads();
        // prefetch next tile (global loads in flight during compute)
        if (tt + 1 < NT) {
            int jn = j0 + (tt + 1) * TJ;
            if (t < TJ) {
                const float* yp = y + (size_t)(jn + t) * 3;
                a0 = yp[0]; a1 = yp[1]; a2 = yp[2];
            }
            const float* fp0 = fea + (size_t)(jn + (t >> 2)) * DFEA + (t & 3) * 4;
            f0 = *(const float4*)fp0;
            f1 = *(const float4*)(fp0 + 64 * DFEA);
        }
        const float* bp = buf;
        #pragma unroll 2
        for (int jj = 0; jj < TJ; ++jj) {
            const float* r = bp + jj * REC;
            float4 yv = *(const float4*)r;                  // broadcast b128
            float dx = x0 - yv.x;
            float dy = x1 - yv.y;
            float dz = x2 - yv.z;
            float d2 = fmaf(dx, dx, fmaf(dy, dy, dz * dz));
            float w  = exp2f(fmaf(d2, -CC, rmc));
            s += w;
            float2 w2 = make_float2(w, w);
            const float2* fq = (const float2*)(r + 4);      // 4x broadcast b128
            #pragma unroll
            for (int k = 0; k < 8; ++k) {
                float2 v = fq[k];
                acc[k].x = fmaf(w2.x, v.x, acc[k].x);       // -> v_pk_fma_f32
                acc[k].y = fmaf(w2.y, v.y, acc[k].y);
            }
        }
        __syncthreads();
        p ^= 1;
    }

    atomicAdd(ssum + row, s);
    float* op = out + (size_t)row * DFEA;
    #pragma unroll
    for (int k = 0; k < 8; ++k) {
        atomicAdd(op + 2 * k + 0, acc[k].x);
        atomicAdd(op + 2 * k + 1, acc[k].y);
    }
}

// ---------------------------------------------------------------- kdiv ----
__global__ __launch_bounds__(256) void kdiv_kernel(float* __restrict__ out,
                                                   const float* __restrict__ ssum) {
    int t = blockIdx.x * 256 + threadIdx.x;
    out[t] = out[t] / ssum[t >> 4];   // s >= 1 guaranteed (w=1 at the rowmin j)
}

// -------------------------------------------------------------- launch ----
extern "C" void kernel_launch(void* const* d_in, const int* in_sizes, int n_in,
                              void* d_out, int out_size, void* d_ws, size_t ws_size,
                              hipStream_t stream) {
    const float* x   = (const float*)d_in[0];   // [N,3]
    const float* y   = (const float*)d_in[1];   // [M,3]
    const float* fea = (const float*)d_in[2];   // [M,16]
    float* out = (float*)d_out;                 // [N,16]

    unsigned int* rowmin = (unsigned int*)d_ws;            // N uints
    float*        ssum   = (float*)d_ws + NROWS;           // N floats

    hipMemsetAsync(d_ws, 0xFF, (size_t)NROWS * 4, stream);          // rowmin sentinel
    hipMemsetAsync((void*)ssum, 0, (size_t)NROWS * 4, stream);
    hipMemsetAsync(d_out, 0, (size_t)NROWS * DFEA * 4, stream);

    kmin_kernel<<<dim3((NROWS / 256) * CHM), 256, 0, stream>>>(x, y, rowmin);
    kacc_kernel<<<dim3((NROWS / 256) * CH), 256, 0, stream>>>(x, y, fea,
                                                              (const float*)rowmin, ssum, out);
    kdiv_kernel<<<dim3((NROWS * DFEA) / 256), 256, 0, stream>>>(out, ssum);
}

// Round 3
// 122.409 us; speedup vs baseline: 4.4170x; 3.1503x over previous
//
#include <hip/hip_runtime.h>
#include <hip/hip_bf16.h>

// GaussSpatialConv: out[i,:] = softmax_j(-||x_i-y_j||^2 * 50) @ y_fea
// B=1, N=M=12288, D=16, fp32.
//
// R3: MFMA/attention-style restructure.
//   g_ij = x_i . (2CC*y_j) - CC|y_j|^2  (prep-packed y4; 3 fma + 1 sub per pair)
//   arg  = g_ij - G_i,  G_i = max_j g_ij  (kmax pass; same fma order => arg<=0)
//   w    = exp2(arg) computed per-lane directly in MFMA A-frag layout
//   out partial = W(bf16) @ feaB(bf16 B-frag, prep kernel) via mfma 16x16x32
//   s_i = sum w via per-lane adds + shfl_xor reduce; combine chunks via atomics.

#define NROWS 12288
#define MCOLS 12288
#define DFEA  16
#define CC 72.13475204444817f   // 50 * log2(e)

typedef __attribute__((ext_vector_type(8))) short bf16x8;
typedef __attribute__((ext_vector_type(4))) float f32x4;

#if __has_builtin(__builtin_amdgcn_exp2f)
#define EXP2(x) __builtin_amdgcn_exp2f(x)
#else
#define EXP2(x) exp2f(x)
#endif

// monotone float<->uint map (works for negative floats) for atomicMax
__device__ __forceinline__ unsigned enc_f(float f) {
    unsigned u = __float_as_uint(f);
    return u ^ ((unsigned)((int)u >> 31) | 0x80000000u);
}
__device__ __forceinline__ float dec_f(unsigned u) {
    unsigned b = (u & 0x80000000u) ? (u ^ 0x80000000u) : ~u;
    return __uint_as_float(b);
}

__device__ __forceinline__ unsigned pk_bf16(float a, float b) {
    __hip_bfloat162 h = __float22bfloat162_rn(make_float2(a, b));
    unsigned u; __builtin_memcpy(&u, &h, 4); return u;
}

// ws float offsets:
//   G    : [0, 12288)            uint-encoded row max of g
//   ssum : [12288, 24576)
//   y4   : [24576, 73728)        float4 {2CC*y0, 2CC*y1, 2CC*y2, -CC*|y|^2}
//   feaB : byte offset 294912    bf16 frag-ordered [384 tiles][64 lanes][8]

// ---------------------------------------------------------------- kprep ----
__global__ __launch_bounds__(256) void kprep_kernel(const float* __restrict__ y,
                                                    const float* __restrict__ fea,
                                                    float4* __restrict__ y4,
                                                    uint4* __restrict__ feaB) {
    int t = blockIdx.x * 256 + threadIdx.x;
    if (t < MCOLS) {
        float a = y[3 * t + 0], b = y[3 * t + 1], c = y[3 * t + 2];
        y4[t] = make_float4(2.0f * CC * a, 2.0f * CC * b, 2.0f * CC * c,
                            -CC * (a * a + b * b + c * c));
    } else {
        int t2   = t - MCOLS;              // [0, 24576)
        int tile = t2 >> 6;
        int lane = t2 & 63;
        int jb   = tile * 32 + ((lane >> 4) << 3);
        int col  = lane & 15;
        float v[8];
        #pragma unroll
        for (int jj = 0; jj < 8; ++jj) v[jj] = fea[(size_t)(jb + jj) * DFEA + col];
        uint4 o;
        o.x = pk_bf16(v[0], v[1]); o.y = pk_bf16(v[2], v[3]);
        o.z = pk_bf16(v[4], v[5]); o.w = pk_bf16(v[6], v[7]);
        feaB[t2] = o;
    }
}

// ---------------------------------------------------------------- kmax ----
// 768 blocks: rb = b/128 (6 row-blocks of 2048 rows), jc = b%128 (96 j's each)
__global__ __launch_bounds__(256) void kmax_kernel(const float* __restrict__ x,
                                                   const float4* __restrict__ y4,
                                                   unsigned* __restrict__ G) {
    __shared__ float4 sm[96];
    int t  = threadIdx.x;
    int rb = blockIdx.x >> 7;
    int jc = blockIdx.x & 127;
    int j0 = jc * 96;
    if (t < 96) sm[t] = y4[j0 + t];
    __syncthreads();

    int wv   = t >> 6;
    int lane = t & 63;
    int r0   = rb * 2048 + wv * 512 + lane;   // rows r0 + 64k, k=0..7

    float X0[8], X1[8], X2[8], mk[8];
    #pragma unroll
    for (int k = 0; k < 8; ++k) {
        int row = r0 + 64 * k;
        X0[k] = x[3 * row + 0]; X1[k] = x[3 * row + 1]; X2[k] = x[3 * row + 2];
        mk[k] = -3.4e38f;
    }

    for (int jj = 0; jj < 96; jj += 4) {
        float4 Ya = sm[jj], Yb = sm[jj + 1], Yc = sm[jj + 2], Yd = sm[jj + 3];
        #pragma unroll
        for (int k = 0; k < 8; ++k) {
            mk[k] = fmaxf(mk[k], fmaf(X0[k], Ya.x, fmaf(X1[k], Ya.y, fmaf(X2[k], Ya.z, Ya.w))));
            mk[k] = fmaxf(mk[k], fmaf(X0[k], Yb.x, fmaf(X1[k], Yb.y, fmaf(X2[k], Yb.z, Yb.w))));
            mk[k] = fmaxf(mk[k], fmaf(X0[k], Yc.x, fmaf(X1[k], Yc.y, fmaf(X2[k], Yc.z, Yc.w))));
            mk[k] = fmaxf(mk[k], fmaf(X0[k], Yd.x, fmaf(X1[k], Yd.y, fmaf(X2[k], Yd.z, Yd.w))));
        }
    }
    #pragma unroll
    for (int k = 0; k < 8; ++k) atomicMax(G + r0 + 64 * k, enc_f(mk[k]));
}

// ---------------------------------------------------------------- kacc ----
// 768 blocks: rb = b>>4 (48 row-blocks of 256 rows), jc = b&15 (768 j's each)
__global__ __launch_bounds__(256, 3) void kacc_kernel(const float* __restrict__ x,
                                                      const float4* __restrict__ y4,
                                                      const uint4* __restrict__ feaB,
                                                      const unsigned* __restrict__ G,
                                                      float* __restrict__ ssum,
                                                      float* __restrict__ out) {
    __shared__ float Ys[4][768];      // SoA y4 chunk: 12 KB
    __shared__ uint4 Fb[1536];        // 24 tiles x 64 lanes b-frags: 24 KB
    int t  = threadIdx.x;
    int rb = blockIdx.x >> 4;
    int jc = blockIdx.x & 15;
    int j0 = jc * 768;

    // stage
    for (int i = t; i < 768; i += 256) {
        float4 v = y4[j0 + i];
        Ys[0][i] = v.x; Ys[1][i] = v.y; Ys[2][i] = v.z; Ys[3][i] = v.w;
    }
    {
        const uint4* fsrc = feaB + (j0 >> 5) * 64;
        for (int i = t; i < 1536; i += 256) Fb[i] = fsrc[i];
    }
    __syncthreads();

    int wv   = t >> 6;
    int lane = t & 63;
    int grp  = lane >> 4;
    int m    = lane & 15;
    int rowbase = rb * 256 + wv * 64;

    float X0[4], X1[4], X2[4], Gm[4];
    #pragma unroll
    for (int r = 0; r < 4; ++r) {
        int row = rowbase + r * 16 + m;
        X0[r] = x[3 * row + 0]; X1[r] = x[3 * row + 1]; X2[r] = x[3 * row + 2];
        Gm[r] = dec_f(G[row]);
    }

    f32x4 acc[4];
    float s[4];
    #pragma unroll
    for (int r = 0; r < 4; ++r) { acc[r] = (f32x4){0.f, 0.f, 0.f, 0.f}; s[r] = 0.f; }

    for (int kt = 0; kt < 24; ++kt) {
        int jb = kt * 32 + grp * 8;   // this lane's 8 k-positions
        float Y0[8], Y1[8], Y2[8], Yw[8];
        *(float4*)&Y0[0] = *(const float4*)&Ys[0][jb];
        *(float4*)&Y0[4] = *(const float4*)&Ys[0][jb + 4];
        *(float4*)&Y1[0] = *(const float4*)&Ys[1][jb];
        *(float4*)&Y1[4] = *(const float4*)&Ys[1][jb + 4];
        *(float4*)&Y2[0] = *(const float4*)&Ys[2][jb];
        *(float4*)&Y2[4] = *(const float4*)&Ys[2][jb + 4];
        *(float4*)&Yw[0] = *(const float4*)&Ys[3][jb];
        *(float4*)&Yw[4] = *(const float4*)&Ys[3][jb + 4];
        uint4 bfv = Fb[kt * 64 + lane];
        bf16x8 bfrag = __builtin_bit_cast(bf16x8, bfv);

        #pragma unroll
        for (int r = 0; r < 4; ++r) {
            float w[8];
            #pragma unroll
            for (int q = 0; q < 8; ++q) {
                float arg = fmaf(X0[r], Y0[q],
                             fmaf(X1[r], Y1[q],
                              fmaf(X2[r], Y2[q], Yw[q]))) - Gm[r];
                w[q] = EXP2(arg);
                s[r] += w[q];
            }
            union { unsigned u[4]; bf16x8 v; } af;
            af.u[0] = pk_bf16(w[0], w[1]); af.u[1] = pk_bf16(w[2], w[3]);
            af.u[2] = pk_bf16(w[4], w[5]); af.u[3] = pk_bf16(w[6], w[7]);
            acc[r] = __builtin_amdgcn_mfma_f32_16x16x32_bf16(af.v, bfrag, acc[r], 0, 0, 0);
        }
    }

    // epilogue: s reduce across the 4 k-groups (lanes sharing lane&15), atomics
    #pragma unroll
    for (int r = 0; r < 4; ++r) {
        float v = s[r];
        v += __shfl_xor(v, 16);
        v += __shfl_xor(v, 32);
        if (lane < 16) atomicAdd(ssum + rowbase + r * 16 + lane, v);
        // C/D layout: lane holds C[row = grp*4 + reg][col = m]
        #pragma unroll
        for (int reg = 0; reg < 4; ++reg) {
            int orow = rowbase + r * 16 + grp * 4 + reg;
            atomicAdd(out + (size_t)orow * DFEA + m, acc[r][reg]);
        }
    }
}

// ---------------------------------------------------------------- kdiv ----
__global__ __launch_bounds__(256) void kdiv_kernel(float* __restrict__ out,
                                                   const float* __restrict__ ssum) {
    int t = blockIdx.x * 256 + threadIdx.x;
    out[t] = out[t] / ssum[t >> 4];   // s >= 1 (arg==0 at the argmax j)
}

// -------------------------------------------------------------- launch ----
extern "C" void kernel_launch(void* const* d_in, const int* in_sizes, int n_in,
                              void* d_out, int out_size, void* d_ws, size_t ws_size,
                              hipStream_t stream) {
    const float* x   = (const float*)d_in[0];   // [N,3]
    const float* y   = (const float*)d_in[1];   // [M,3]
    const float* fea = (const float*)d_in[2];   // [M,16]
    float* out = (float*)d_out;                 // [N,16]

    float*    wsf  = (float*)d_ws;
    unsigned* G    = (unsigned*)wsf;                        // 12288 u32
    float*    ssum = wsf + NROWS;                           // 12288 f32
    float4*   y4   = (float4*)(wsf + 2 * NROWS);            // 12288 float4
    uint4*    feaB = (uint4*)(wsf + 2 * NROWS + 4 * NROWS); // 24576 uint4

    hipMemsetAsync((void*)G, 0, (size_t)NROWS * 4, stream);      // enc-min
    hipMemsetAsync((void*)ssum, 0, (size_t)NROWS * 4, stream);
    hipMemsetAsync(d_out, 0, (size_t)NROWS * DFEA * 4, stream);

    kprep_kernel<<<dim3((MCOLS + 24576) / 256), 256, 0, stream>>>(y, fea, y4, feaB);
    kmax_kernel<<<dim3(6 * 128), 256, 0, stream>>>(x, y4, G);
    kacc_kernel<<<dim3(48 * 16), 256, 0, stream>>>(x, y4, feaB, G, ssum, out);
    kdiv_kernel<<<dim3((NROWS * DFEA) / 256), 256, 0, stream>>>(out, ssum);
}